// Round 1
// baseline (223.461 us; speedup 1.0000x reference)
//
#include <hip/hip_runtime.h>
#include <hip/hip_bf16.h>
#include <math.h>

#define NN 4096
#define IN_DIM 256
#define OUT_DIM 128
#define HEADS 4
#define SUB 32
#define MAXDEG 128
#define ETA 0.5f
#define INV_SQRT_SUB 0.17677669529663687f

// ---------------- K0: build neighbor lists from dense mask ----------------
__global__ __launch_bounds__(256) void build_nbrs(const float* __restrict__ adj,
                                                  int* __restrict__ nbr,
                                                  int* __restrict__ deg) {
    int i = blockIdx.x;
    int t = threadIdx.x;
    __shared__ int cnt;
    if (t == 0) cnt = 0;
    __syncthreads();
    const float* row = adj + (size_t)i * NN;
    #pragma unroll
    for (int k = 0; k < NN / 256; ++k) {
        int j = t + k * 256;           // coalesced across threads
        float v = row[j];
        if (v > 0.5f) {
            int p = atomicAdd(&cnt, 1);
            if (p < MAXDEG) nbr[i * MAXDEG + p] = j;
        }
    }
    __syncthreads();
    if (t == 0) deg[i] = cnt < MAXDEG ? cnt : MAXDEG;
}

// ---------------- K1: ZT = H @ U_h  (per head), P = H @ proj_w^T ----------------
#define ROWS 16
__global__ __launch_bounds__(128) void compute_zt_p(const float* __restrict__ H,
                                                    const float* __restrict__ U,
                                                    const float* __restrict__ PW,
                                                    float* __restrict__ ZT,
                                                    float* __restrict__ P) {
    int t = threadIdx.x;               // 128 threads: t = h*32+s, also t = o
    int r0 = blockIdx.x * ROWS;
    __shared__ float Hs[ROWS][IN_DIM];
    #pragma unroll
    for (int k = 0; k < ROWS * IN_DIM / 128; ++k) {
        int idx = t + k * 128;
        Hs[idx / IN_DIM][idx % IN_DIM] = H[(size_t)r0 * IN_DIM + idx];
    }
    __syncthreads();
    int h = t >> 5, s = t & 31;
    float accZ[ROWS], accP[ROWS];
    #pragma unroll
    for (int r = 0; r < ROWS; ++r) { accZ[r] = 0.f; accP[r] = 0.f; }
    const float* Uc = U + h * IN_DIM * SUB + s;   // U[h][d][s], stride SUB over d
    const float* Wc = PW + t * IN_DIM;            // proj_w[o][d]
    for (int d = 0; d < IN_DIM; ++d) {
        float u = Uc[d * SUB];
        float w = Wc[d];
        #pragma unroll
        for (int r = 0; r < ROWS; ++r) {
            float hv = Hs[r][d];                  // LDS broadcast
            accZ[r] += hv * u;
            accP[r] += hv * w;
        }
    }
    #pragma unroll
    for (int r = 0; r < ROWS; ++r) {
        ZT[(size_t)(r0 + r) * 128 + t] = accZ[r];
        P[(size_t)(r0 + r) * 128 + t]  = accP[r];
    }
}

// ---------------- K2: W2[hs][o] = sum_d U[h][d][s] * proj_w[o][d] ----------------
__global__ __launch_bounds__(128) void compute_w2(const float* __restrict__ U,
                                                  const float* __restrict__ PW,
                                                  float* __restrict__ W2) {
    int hs = blockIdx.x;   // 128 blocks
    int o  = threadIdx.x;  // 128 threads
    int h = hs >> 5, s = hs & 31;
    const float* Uc = U + h * IN_DIM * SUB + s;
    const float* Wc = PW + o * IN_DIM;
    float acc = 0.f;
    for (int d = 0; d < IN_DIM; ++d) acc += Uc[d * SUB] * Wc[d];
    W2[hs * OUT_DIM + o] = acc;
}

// ---------------- K3: orthogonality loss ----------------
__global__ __launch_bounds__(256) void orth_loss_kernel(const float* __restrict__ U,
                                                        float* __restrict__ out_loss) {
    const int pk[10] = {0,0,0,0,1,1,1,2,2,3};
    const int pl[10] = {0,1,2,3,1,2,3,2,3,3};
    int p = blockIdx.x;          // 10 blocks, one per (k<=l) pair
    int k = pk[p], l = pl[p];
    int t = threadIdx.x;         // 256 threads
    float local = 0.f;
    for (int e = t; e < SUB * SUB; e += 256) {
        int s  = e >> 5;
        int t2 = e & 31;
        const float* Uk = U + k * IN_DIM * SUB + s;
        const float* Ul = U + l * IN_DIM * SUB + t2;
        float g = 0.f;
        for (int d = 0; d < IN_DIM; ++d) g += Uk[d * SUB] * Ul[d * SUB];
        float sub = g - ((k == l && s == t2) ? 1.f : 0.f);
        local += sub * sub;
    }
    __shared__ float red[256];
    red[t] = local;
    __syncthreads();
    for (int off = 128; off > 0; off >>= 1) {
        if (t < off) red[t] += red[t + off];
        __syncthreads();
    }
    if (t == 0) atomicAdd(out_loss, red[0]);
}

// ---------------- K4: sparse attention + aggregation + fused epilogue ----------------
__global__ __launch_bounds__(128) void sparse_attn(const float* __restrict__ ZT,
                                                   const float* __restrict__ P,
                                                   const float* __restrict__ W2,
                                                   const int* __restrict__ nbr,
                                                   const int* __restrict__ deg,
                                                   const float* __restrict__ threshold,
                                                   float* __restrict__ out) {
    int i = blockIdx.x;
    int t = threadIdx.x;      // 128: (h,s) for attention, o for epilogue
    int h = t >> 5, s = t & 31;
    __shared__ int   nbr_s[MAXDEG];
    __shared__ float score_s[MAXDEG * HEADS];
    __shared__ float agg_s[128];

    int dg = deg[i];
    if (t < dg) nbr_s[t] = nbr[i * MAXDEG + t];
    float q = ZT[(size_t)i * 128 + t];
    __syncthreads();

    // pass 1: scores_hj = <ZT[i][h], ZT[j][h]> / sqrt(SUB)
    for (int jj = 0; jj < dg; ++jj) {
        int j = nbr_s[jj];
        float v = ZT[(size_t)j * 128 + t];   // coalesced 512B row, L2-resident
        float prod = q * v;
        prod += __shfl_xor(prod, 16, 32);
        prod += __shfl_xor(prod, 8, 32);
        prod += __shfl_xor(prod, 4, 32);
        prod += __shfl_xor(prod, 2, 32);
        prod += __shfl_xor(prod, 1, 32);
        if (s == 0) score_s[jj * HEADS + h] = prod * INV_SQRT_SUB;
    }
    __syncthreads();

    // per-head softmax over dg entries (32 lanes of each head cooperate)
    float m = -1e30f;
    for (int jj = s; jj < dg; jj += 32) m = fmaxf(m, score_s[jj * HEADS + h]);
    m = fmaxf(m, __shfl_xor(m, 16, 32));
    m = fmaxf(m, __shfl_xor(m, 8, 32));
    m = fmaxf(m, __shfl_xor(m, 4, 32));
    m = fmaxf(m, __shfl_xor(m, 2, 32));
    m = fmaxf(m, __shfl_xor(m, 1, 32));
    float sum = 0.f;
    for (int jj = s; jj < dg; jj += 32) {
        float e = __expf(score_s[jj * HEADS + h] - m);
        score_s[jj * HEADS + h] = e;
        sum += e;
    }
    sum += __shfl_xor(sum, 16, 32);
    sum += __shfl_xor(sum, 8, 32);
    sum += __shfl_xor(sum, 4, 32);
    sum += __shfl_xor(sum, 2, 32);
    sum += __shfl_xor(sum, 1, 32);
    float inv = 1.f / sum;
    __syncthreads();

    // pass 2: agg[h][s] = sum_j alpha_hj * ZT[j][h][s]   (fold in eta*inv)
    float acc = 0.f;
    for (int jj = 0; jj < dg; ++jj) {
        int j = nbr_s[jj];
        float a = score_s[jj * HEADS + h];   // LDS broadcast within head group
        acc += a * ZT[(size_t)j * 128 + t];
    }
    agg_s[t] = acc * inv * ETA;
    __syncthreads();

    // epilogue: out[o] = P[i][o] + sum_hs agg[hs]*W2[hs][o], then soft-threshold
    int o = t;
    float val = P[(size_t)i * 128 + o];
    for (int hs = 0; hs < 128; ++hs) {
        val += agg_s[hs] * W2[hs * 128 + o];  // W2 coalesced, agg_s broadcast
    }
    float thr = threshold[o];
    float av = fabsf(val) - thr;
    out[(size_t)i * 128 + o] = (av > 0.f) ? copysignf(av, val) : 0.f;
}

extern "C" void kernel_launch(void* const* d_in, const int* in_sizes, int n_in,
                              void* d_out, int out_size, void* d_ws, size_t ws_size,
                              hipStream_t stream) {
    const float* H   = (const float*)d_in[0];
    const float* adj = (const float*)d_in[1];
    const float* U   = (const float*)d_in[2];
    const float* thr = (const float*)d_in[3];
    const float* PW  = (const float*)d_in[4];
    float* out = (float*)d_out;

    char* ws = (char*)d_ws;
    float* ZT  = (float*)(ws);                         // 2 MB
    float* P   = (float*)(ws + (size_t)2097152);       // 2 MB
    float* W2  = (float*)(ws + (size_t)4194304);       // 64 KB
    int*   nbr = (int*)  (ws + (size_t)4259840);       // 2 MB
    int*   deg = (int*)  (ws + (size_t)6356992);       // 16 KB

    build_nbrs<<<NN, 256, 0, stream>>>(adj, nbr, deg);
    compute_zt_p<<<NN / ROWS, 128, 0, stream>>>(H, U, PW, ZT, P);
    compute_w2<<<128, 128, 0, stream>>>(U, PW, W2);

    // loss accumulator must be zeroed (d_out is poisoned before each run)
    hipMemsetAsync(out + (size_t)NN * OUT_DIM, 0, sizeof(float), stream);
    orth_loss_kernel<<<10, 256, 0, stream>>>(U, out + (size_t)NN * OUT_DIM);

    sparse_attn<<<NN, 128, 0, stream>>>(ZT, P, W2, nbr, deg, thr, out);
}

// Round 2
// 212.239 us; speedup vs baseline: 1.0529x; 1.0529x over previous
//
#include <hip/hip_runtime.h>
#include <hip/hip_bf16.h>
#include <math.h>

#define NN 4096
#define IN_DIM 256
#define OUT_DIM 128
#define HEADS 4
#define SUB 32
#define MAXDEG 128
#define ETA 0.5f
#define INV_SQRT_SUB 0.17677669529663687f

// ---------------- K0: Wcomb[d][c] = [U cols | PW^T cols], c-contiguous ----------------
__global__ __launch_bounds__(256) void prep_w(const float* __restrict__ U,
                                              const float* __restrict__ PW,
                                              float* __restrict__ Wcomb) {
    int d = blockIdx.x;      // 256
    int c = threadIdx.x;     // 256
    float v;
    if (c < 128) {
        int h = c >> 5, s = c & 31;
        v = U[h * IN_DIM * SUB + d * SUB + s];
    } else {
        int o = c - 128;
        v = PW[o * IN_DIM + d];           // transposed read (L2-served, tiny)
    }
    Wcomb[d * 256 + c] = v;
}

// ---------------- K1: [ZT | P] = H @ Wcomb  ----------------
#define RPB 8
__global__ __launch_bounds__(256) void compute_zt_p(const float* __restrict__ H,
                                                    const float* __restrict__ Wcomb,
                                                    float* __restrict__ ZT,
                                                    float* __restrict__ P) {
    int t = threadIdx.x;                  // output column c (0..255)
    int r0 = blockIdx.x * RPB;
    __shared__ float Hs[RPB][IN_DIM];     // 8 KB
    const float4* H4 = (const float4*)(H + (size_t)r0 * IN_DIM);
    float4* Hs4 = (float4*)&Hs[0][0];
    Hs4[t]       = H4[t];
    Hs4[t + 256] = H4[t + 256];
    __syncthreads();

    float acc[RPB];
    #pragma unroll
    for (int r = 0; r < RPB; ++r) acc[r] = 0.f;

    for (int d4 = 0; d4 < IN_DIM; d4 += 4) {
        float w0 = Wcomb[(d4 + 0) * 256 + t];   // coalesced 1KB wave loads
        float w1 = Wcomb[(d4 + 1) * 256 + t];
        float w2 = Wcomb[(d4 + 2) * 256 + t];
        float w3 = Wcomb[(d4 + 3) * 256 + t];
        #pragma unroll
        for (int r = 0; r < RPB; ++r) {
            float4 hv = *(const float4*)&Hs[r][d4];   // LDS broadcast b128
            acc[r] += hv.x * w0 + hv.y * w1 + hv.z * w2 + hv.w * w3;
        }
    }
    #pragma unroll
    for (int r = 0; r < RPB; ++r) {
        if (t < 128) ZT[(size_t)(r0 + r) * 128 + t] = acc[r];
        else         P [(size_t)(r0 + r) * 128 + (t - 128)] = acc[r];
    }
}

// ---------------- K2: W2[hs][o] = sum_d Wcomb[d][hs] * Wcomb[d][128+o] ----------------
__global__ __launch_bounds__(128) void compute_w2(const float* __restrict__ Wcomb,
                                                  float* __restrict__ W2) {
    int hs = blockIdx.x;   // 128
    int o  = threadIdx.x;  // 128
    float acc = 0.f;
    #pragma unroll 4
    for (int d = 0; d < IN_DIM; ++d) {
        float u = Wcomb[d * 256 + hs];        // scalar broadcast (uniform per block)
        float w = Wcomb[d * 256 + 128 + o];   // coalesced
        acc += u * w;
    }
    W2[hs * OUT_DIM + o] = acc;
}

// ---------------- K3: orthogonality loss ----------------
__global__ __launch_bounds__(256) void orth_loss_kernel(const float* __restrict__ U,
                                                        float* __restrict__ out_loss) {
    const int pk[10] = {0,0,0,0,1,1,1,2,2,3};
    const int pl[10] = {0,1,2,3,1,2,3,2,3,3};
    int p = blockIdx.x;          // 10 blocks, one per (k<=l) pair
    int k = pk[p], l = pl[p];
    int t = threadIdx.x;         // 256 threads
    float local = 0.f;
    for (int e = t; e < SUB * SUB; e += 256) {
        int s  = e >> 5;
        int t2 = e & 31;
        const float* Uk = U + k * IN_DIM * SUB + s;
        const float* Ul = U + l * IN_DIM * SUB + t2;
        float g = 0.f;
        #pragma unroll 4
        for (int d = 0; d < IN_DIM; ++d) g += Uk[d * SUB] * Ul[d * SUB];
        float sub = g - ((k == l && s == t2) ? 1.f : 0.f);
        local += sub * sub;
    }
    __shared__ float red[256];
    red[t] = local;
    __syncthreads();
    for (int off = 128; off > 0; off >>= 1) {
        if (t < off) red[t] += red[t + off];
        __syncthreads();
    }
    if (t == 0) atomicAdd(out_loss, red[0]);
}

// ---------------- K4: fused adj-scan + sparse attention + epilogue ----------------
__global__ __launch_bounds__(128) void sparse_attn(const float* __restrict__ ZT,
                                                   const float* __restrict__ Pm,
                                                   const float* __restrict__ W2,
                                                   const float* __restrict__ adj,
                                                   const float* __restrict__ threshold,
                                                   float* __restrict__ out) {
    int i = blockIdx.x;
    int t = threadIdx.x;      // 128: (h,s) for attention, o for epilogue
    int h = t >> 5, s = t & 31;
    __shared__ int   nbr_s[MAXDEG];
    __shared__ float score_s[MAXDEG * HEADS];
    __shared__ float agg_s[128];
    __shared__ int cnt;
    if (t == 0) cnt = 0;
    __syncthreads();

    // ---- scan the adjacency row (16 KB, float4 coalesced) ----
    const float4* row4 = (const float4*)(adj + (size_t)i * NN);
    #pragma unroll
    for (int k = 0; k < NN / (128 * 4); ++k) {      // 8 iterations
        float4 v = row4[t + k * 128];
        int j0 = (t + k * 128) * 4;
        if (v.x > 0.5f) { int p = atomicAdd(&cnt, 1); if (p < MAXDEG) nbr_s[p] = j0; }
        if (v.y > 0.5f) { int p = atomicAdd(&cnt, 1); if (p < MAXDEG) nbr_s[p] = j0 + 1; }
        if (v.z > 0.5f) { int p = atomicAdd(&cnt, 1); if (p < MAXDEG) nbr_s[p] = j0 + 2; }
        if (v.w > 0.5f) { int p = atomicAdd(&cnt, 1); if (p < MAXDEG) nbr_s[p] = j0 + 3; }
    }
    __syncthreads();
    int dg = cnt < MAXDEG ? cnt : MAXDEG;

    float q = ZT[(size_t)i * 128 + t];

    // ---- pass 1: scores ----
    for (int jj = 0; jj < dg; ++jj) {
        int j = nbr_s[jj];
        float v = ZT[(size_t)j * 128 + t];   // 512B row, L2-resident
        float prod = q * v;
        prod += __shfl_xor(prod, 16, 32);
        prod += __shfl_xor(prod, 8, 32);
        prod += __shfl_xor(prod, 4, 32);
        prod += __shfl_xor(prod, 2, 32);
        prod += __shfl_xor(prod, 1, 32);
        if (s == 0) score_s[jj * HEADS + h] = prod * INV_SQRT_SUB;
    }
    __syncthreads();

    // ---- per-head softmax over dg entries ----
    float m = -1e30f;
    for (int jj = s; jj < dg; jj += 32) m = fmaxf(m, score_s[jj * HEADS + h]);
    m = fmaxf(m, __shfl_xor(m, 16, 32));
    m = fmaxf(m, __shfl_xor(m, 8, 32));
    m = fmaxf(m, __shfl_xor(m, 4, 32));
    m = fmaxf(m, __shfl_xor(m, 2, 32));
    m = fmaxf(m, __shfl_xor(m, 1, 32));
    float sum = 0.f;
    for (int jj = s; jj < dg; jj += 32) {
        float e = __expf(score_s[jj * HEADS + h] - m);
        score_s[jj * HEADS + h] = e;
        sum += e;
    }
    sum += __shfl_xor(sum, 16, 32);
    sum += __shfl_xor(sum, 8, 32);
    sum += __shfl_xor(sum, 4, 32);
    sum += __shfl_xor(sum, 2, 32);
    sum += __shfl_xor(sum, 1, 32);
    float inv = 1.f / sum;
    __syncthreads();

    // ---- pass 2: weighted aggregation ----
    float acc = 0.f;
    for (int jj = 0; jj < dg; ++jj) {
        int j = nbr_s[jj];
        float a = score_s[jj * HEADS + h];
        acc += a * ZT[(size_t)j * 128 + t];
    }
    agg_s[t] = acc * inv * ETA;
    __syncthreads();

    // ---- epilogue: out = P + agg @ W2, soft-threshold ----
    float val = Pm[(size_t)i * 128 + t];
    const float4* agg4 = (const float4*)agg_s;
    #pragma unroll 4
    for (int q4 = 0; q4 < 32; ++q4) {
        float4 a = agg4[q4];
        int hs = q4 * 4;
        val += a.x * W2[(hs + 0) * 128 + t]
             + a.y * W2[(hs + 1) * 128 + t]
             + a.z * W2[(hs + 2) * 128 + t]
             + a.w * W2[(hs + 3) * 128 + t];
    }
    float thr = threshold[t];
    float av = fabsf(val) - thr;
    out[(size_t)i * 128 + t] = (av > 0.f) ? copysignf(av, val) : 0.f;
}

extern "C" void kernel_launch(void* const* d_in, const int* in_sizes, int n_in,
                              void* d_out, int out_size, void* d_ws, size_t ws_size,
                              hipStream_t stream) {
    const float* H   = (const float*)d_in[0];
    const float* adj = (const float*)d_in[1];
    const float* U   = (const float*)d_in[2];
    const float* thr = (const float*)d_in[3];
    const float* PW  = (const float*)d_in[4];
    float* out = (float*)d_out;

    char* ws = (char*)d_ws;
    float* ZT    = (float*)(ws);                       // 2 MB
    float* P     = (float*)(ws + (size_t)2097152);     // 2 MB
    float* W2    = (float*)(ws + (size_t)4194304);     // 64 KB
    float* Wcomb = (float*)(ws + (size_t)4259840);     // 256 KB

    hipMemsetAsync(out + (size_t)NN * OUT_DIM, 0, sizeof(float), stream);

    prep_w<<<256, 256, 0, stream>>>(U, PW, Wcomb);
    compute_zt_p<<<NN / RPB, 256, 0, stream>>>(H, Wcomb, ZT, P);
    compute_w2<<<128, 128, 0, stream>>>(Wcomb, W2);
    orth_loss_kernel<<<10, 256, 0, stream>>>(U, out + (size_t)NN * OUT_DIM);
    sparse_attn<<<NN, 128, 0, stream>>>(ZT, P, W2, adj, thr, out);
}

// Round 3
// 169.608 us; speedup vs baseline: 1.3175x; 1.2514x over previous
//
#include <hip/hip_runtime.h>
#include <hip/hip_bf16.h>
#include <math.h>

#define NN 4096
#define IN_DIM 256
#define OUT_DIM 128
#define HEADS 4
#define SUB 32
#define MAXDEG 128
#define ETA 0.5f
#define INV_SQRT_SUB 0.17677669529663687f

// ---- K0 (fused small): prep Wcomb[c][d] | W2[hs][o] | orth loss ----
__global__ __launch_bounds__(256) void fused_small(const float* __restrict__ U,
                                                   const float* __restrict__ PW,
                                                   float* __restrict__ Wcomb,
                                                   float* __restrict__ W2,
                                                   float* __restrict__ loss) {
    int b = blockIdx.x;
    int t = threadIdx.x;
    __shared__ float sh[260];

    if (b < 256) {
        // Wcomb row c=b over d=t (c<128: U column (h,s); c>=128: PW row)
        float v;
        if (b < 128) {
            int h = b >> 5, s = b & 31;
            v = U[h * IN_DIM * SUB + t * SUB + s];
        } else {
            v = PW[(b - 128) * IN_DIM + t];
        }
        Wcomb[b * IN_DIM + t] = v;
    } else if (b < 384) {
        // W2[hs][o] = <U[:,hs], PW[o,:]>
        int hs = b - 256;
        int h = hs >> 5, s = hs & 31;
        sh[t] = U[h * IN_DIM * SUB + t * SUB + s];
        __syncthreads();
        if (t < 128) {
            const float4* pw4 = (const float4*)(PW + t * IN_DIM);
            const float4* u4  = (const float4*)sh;
            float acc = 0.f;
            #pragma unroll 4
            for (int d4 = 0; d4 < 64; ++d4) {
                float4 a = u4[d4], p = pw4[d4];
                acc += a.x * p.x + a.y * p.y + a.z * p.z + a.w * p.w;
            }
            W2[hs * OUT_DIM + t] = acc;
        }
    } else {
        // orth loss: pair p = b-384
        const int pk[10] = {0,0,0,0,1,1,1,2,2,3};
        const int pl[10] = {0,1,2,3,1,2,3,2,3,3};
        int p = b - 384;
        int k = pk[p], l = pl[p];
        int t2 = t & 31;
        int sg = t >> 5;           // 8 groups, 4 s-values each
        const float* Uk = U + k * IN_DIM * SUB;
        const float* Ul = U + l * IN_DIM * SUB;
        float a0 = 0.f, a1 = 0.f, a2 = 0.f, a3 = 0.f;
        #pragma unroll 4
        for (int d = 0; d < IN_DIM; ++d) {
            float ul = Ul[d * SUB + t2];           // one 128B line per d
            float u0 = Uk[d * SUB + sg * 4 + 0];
            float u1 = Uk[d * SUB + sg * 4 + 1];
            float u2 = Uk[d * SUB + sg * 4 + 2];
            float u3 = Uk[d * SUB + sg * 4 + 3];
            a0 += u0 * ul; a1 += u1 * ul; a2 += u2 * ul; a3 += u3 * ul;
        }
        if (k == l) {
            if (sg * 4 + 0 == t2) a0 -= 1.f;
            if (sg * 4 + 1 == t2) a1 -= 1.f;
            if (sg * 4 + 2 == t2) a2 -= 1.f;
            if (sg * 4 + 3 == t2) a3 -= 1.f;
        }
        float local = a0 * a0 + a1 * a1 + a2 * a2 + a3 * a3;
        local += __shfl_xor(local, 32, 64);
        local += __shfl_xor(local, 16, 64);
        local += __shfl_xor(local, 8, 64);
        local += __shfl_xor(local, 4, 64);
        local += __shfl_xor(local, 2, 64);
        local += __shfl_xor(local, 1, 64);
        if ((t & 63) == 0) sh[256 + (t >> 6)] = local;
        __syncthreads();
        if (t == 0) atomicAdd(loss, sh[256] + sh[257] + sh[258] + sh[259]);
    }
}

// ---- K1: [ZT | P] = H @ Wcomb^T  (Wcomb rows = output columns) ----
#define RPB 8
__global__ __launch_bounds__(256) void compute_zt_p(const float* __restrict__ H,
                                                    const float* __restrict__ Wcomb,
                                                    float* __restrict__ ZT,
                                                    float* __restrict__ P) {
    int t = threadIdx.x;                  // output column c (0..255)
    int r0 = blockIdx.x * RPB;
    __shared__ float Hs[RPB][IN_DIM];     // 8 KB
    const float4* H4 = (const float4*)(H + (size_t)r0 * IN_DIM);
    float4* Hs4 = (float4*)&Hs[0][0];
    Hs4[t]       = H4[t];
    Hs4[t + 256] = H4[t + 256];
    __syncthreads();

    float acc[RPB];
    #pragma unroll
    for (int r = 0; r < RPB; ++r) acc[r] = 0.f;

    const float4* Wr = (const float4*)(Wcomb + t * IN_DIM);   // thread's own row
    float4 w = Wr[0];
    #pragma unroll 4
    for (int d4 = 0; d4 < 64; ++d4) {
        float4 wn = Wr[(d4 + 1 < 64) ? d4 + 1 : 63];          // prefetch next
        #pragma unroll
        for (int r = 0; r < RPB; ++r) {
            float4 h = *(const float4*)&Hs[r][d4 * 4];        // uniform broadcast
            acc[r] += h.x * w.x + h.y * w.y + h.z * w.z + h.w * w.w;
        }
        w = wn;
    }
    #pragma unroll
    for (int r = 0; r < RPB; ++r) {
        if (t < 128) ZT[(size_t)(r0 + r) * 128 + t] = acc[r];
        else         P [(size_t)(r0 + r) * 128 + (t - 128)] = acc[r];
    }
}

// ---- K2: fused adj-scan + single-pass attention -> agg (ETA/sum folded) ----
__global__ __launch_bounds__(128) void attn_core(const float* __restrict__ ZT,
                                                 const float* __restrict__ adj,
                                                 float* __restrict__ agg) {
    int i = blockIdx.x;
    int t = threadIdx.x;
    __shared__ int nbr_s[MAXDEG];
    __shared__ int cnt;
    if (t == 0) cnt = 0;
    __syncthreads();

    const float4* row4 = (const float4*)(adj + (size_t)i * NN);
    #pragma unroll
    for (int k2 = 0; k2 < NN / (128 * 4); ++k2) {
        float4 v = row4[t + k2 * 128];
        int j0 = (t + k2 * 128) * 4;
        if (v.x > 0.5f) { int p = atomicAdd(&cnt, 1); if (p < MAXDEG) nbr_s[p] = j0; }
        if (v.y > 0.5f) { int p = atomicAdd(&cnt, 1); if (p < MAXDEG) nbr_s[p] = j0 + 1; }
        if (v.z > 0.5f) { int p = atomicAdd(&cnt, 1); if (p < MAXDEG) nbr_s[p] = j0 + 2; }
        if (v.w > 0.5f) { int p = atomicAdd(&cnt, 1); if (p < MAXDEG) nbr_s[p] = j0 + 3; }
    }
    __syncthreads();
    int dg = cnt < MAXDEG ? cnt : MAXDEG;

    float q = ZT[(size_t)i * 128 + t];
    float accV = 0.f, accS = 0.f;

    for (int jj = 0; jj < dg; jj += 4) {
        int i0 = nbr_s[jj];
        int i1 = nbr_s[(jj + 1 < dg) ? jj + 1 : jj];
        int i2 = nbr_s[(jj + 2 < dg) ? jj + 2 : jj];
        int i3 = nbr_s[(jj + 3 < dg) ? jj + 3 : jj];
        float v0 = ZT[(size_t)i0 * 128 + t];
        float v1 = ZT[(size_t)i1 * 128 + t];
        float v2 = ZT[(size_t)i2 * 128 + t];
        float v3 = ZT[(size_t)i3 * 128 + t];
        float p0 = q * v0, p1 = q * v1, p2 = q * v2, p3 = q * v3;
        p0 += __shfl_xor(p0, 16, 32); p1 += __shfl_xor(p1, 16, 32);
        p2 += __shfl_xor(p2, 16, 32); p3 += __shfl_xor(p3, 16, 32);
        p0 += __shfl_xor(p0, 8, 32);  p1 += __shfl_xor(p1, 8, 32);
        p2 += __shfl_xor(p2, 8, 32);  p3 += __shfl_xor(p3, 8, 32);
        p0 += __shfl_xor(p0, 4, 32);  p1 += __shfl_xor(p1, 4, 32);
        p2 += __shfl_xor(p2, 4, 32);  p3 += __shfl_xor(p3, 4, 32);
        p0 += __shfl_xor(p0, 2, 32);  p1 += __shfl_xor(p1, 2, 32);
        p2 += __shfl_xor(p2, 2, 32);  p3 += __shfl_xor(p3, 2, 32);
        p0 += __shfl_xor(p0, 1, 32);  p1 += __shfl_xor(p1, 1, 32);
        p2 += __shfl_xor(p2, 1, 32);  p3 += __shfl_xor(p3, 1, 32);
        float e0 = __expf(p0 * INV_SQRT_SUB);
        float e1 = (jj + 1 < dg) ? __expf(p1 * INV_SQRT_SUB) : 0.f;
        float e2 = (jj + 2 < dg) ? __expf(p2 * INV_SQRT_SUB) : 0.f;
        float e3 = (jj + 3 < dg) ? __expf(p3 * INV_SQRT_SUB) : 0.f;
        accV += e0 * v0 + e1 * v1 + e2 * v2 + e3 * v3;
        accS += e0 + e1 + e2 + e3;
    }
    agg[(size_t)i * 128 + t] = accV * (ETA / accS);
}

// ---- K3: epilogue out = soft_thresh(P + agg @ W2) with 16-row W2 reuse ----
#define EROWS 16
__global__ __launch_bounds__(256) void epilogue(const float* __restrict__ Pm,
                                                const float* __restrict__ agg,
                                                const float* __restrict__ W2,
                                                const float* __restrict__ threshold,
                                                float* __restrict__ out) {
    int t = threadIdx.x;
    int o = t & 127, half = t >> 7;
    int r0 = blockIdx.x * EROWS;
    __shared__ float As[EROWS][128];     // 8 KB
    const float4* a4 = (const float4*)(agg + (size_t)r0 * 128);
    float4* As4 = (float4*)&As[0][0];
    As4[t]       = a4[t];
    As4[t + 256] = a4[t + 256];
    __syncthreads();

    float acc[8];
    #pragma unroll
    for (int r = 0; r < 8; ++r) acc[r] = 0.f;

    for (int q4 = 0; q4 < 32; ++q4) {
        int hs = q4 * 4;
        float w0 = W2[(hs + 0) * 128 + o];
        float w1 = W2[(hs + 1) * 128 + o];
        float w2v = W2[(hs + 2) * 128 + o];
        float w3 = W2[(hs + 3) * 128 + o];
        #pragma unroll
        for (int r = 0; r < 8; ++r) {
            float4 a = *(const float4*)&As[half * 8 + r][hs];   // uniform broadcast
            acc[r] += a.x * w0 + a.y * w1 + a.z * w2v + a.w * w3;
        }
    }
    float th = threshold[o];
    #pragma unroll
    for (int r = 0; r < 8; ++r) {
        int row = r0 + half * 8 + r;
        float val = Pm[(size_t)row * 128 + o] + acc[r];
        float av = fabsf(val) - th;
        out[(size_t)row * 128 + o] = (av > 0.f) ? copysignf(av, val) : 0.f;
    }
}

extern "C" void kernel_launch(void* const* d_in, const int* in_sizes, int n_in,
                              void* d_out, int out_size, void* d_ws, size_t ws_size,
                              hipStream_t stream) {
    const float* H   = (const float*)d_in[0];
    const float* adj = (const float*)d_in[1];
    const float* U   = (const float*)d_in[2];
    const float* thr = (const float*)d_in[3];
    const float* PW  = (const float*)d_in[4];
    float* out = (float*)d_out;
    float* loss = out + (size_t)NN * OUT_DIM;

    char* ws = (char*)d_ws;
    float* ZT    = (float*)(ws);                       // 2 MB
    float* P     = (float*)(ws + (size_t)2097152);     // 2 MB
    float* agg   = (float*)(ws + (size_t)4194304);     // 2 MB
    float* W2    = (float*)(ws + (size_t)6291456);     // 64 KB
    float* Wcomb = (float*)(ws + (size_t)6356992);     // 256 KB

    hipMemsetAsync(loss, 0, sizeof(float), stream);
    fused_small<<<394, 256, 0, stream>>>(U, PW, Wcomb, W2, loss);
    compute_zt_p<<<NN / RPB, 256, 0, stream>>>(H, Wcomb, ZT, P);
    attn_core<<<NN, 128, 0, stream>>>(ZT, adj, agg);
    epilogue<<<NN / EROWS, 256, 0, stream>>>(P, agg, W2, thr, out);
}